// Round 6
// baseline (198.601 us; speedup 1.0000x reference)
//
#include <hip/hip_runtime.h>

#define F16 _Float16
typedef __attribute__((ext_vector_type(8))) _Float16 half8;
typedef __attribute__((ext_vector_type(4))) _Float16 half4;
typedef __attribute__((ext_vector_type(4))) float f32x4;

constexpr int S = 2048;
constexpr int E = 2048;
constexpr float MASK_NEG = -66504.0f;
constexpr float INV_SQRT_D = 0.08838834764831845f;  // 1/sqrt(128)
constexpr float MASK_SC = MASK_NEG * INV_SQRT_D;    // mask applied to pre-scaled scores

__device__ __forceinline__ void gload16(const void* g, void* l) {
  __builtin_amdgcn_global_load_lds((const __attribute__((address_space(1))) void*)g,
                                   (__attribute__((address_space(3))) void*)l, 16, 0, 0);
}

// ---------------- elementwise f32 -> f16 cast ----------------
__global__ __launch_bounds__(256) void cast_f32_f16_k(const float* __restrict__ x,
                                                      F16* __restrict__ y) {
  size_t i = ((size_t)blockIdx.x * 256 + threadIdx.x) * 8;
  float4 a = *(const float4*)(x + i);
  float4 b = *(const float4*)(x + i + 4);
  half8 h;
  h[0] = (F16)a.x; h[1] = (F16)a.y; h[2] = (F16)a.z; h[3] = (F16)a.w;
  h[4] = (F16)b.x; h[5] = (F16)b.y; h[6] = (F16)b.z; h[7] = (F16)b.w;
  *(half8*)(y + i) = h;
}

// ---------------- dual f32 [E][E] -> f16 transposed [E][E] ----------------
__global__ __launch_bounds__(256) void transpose_cast2_k(const float* __restrict__ W0,
                                                         const float* __restrict__ W1,
                                                         F16* __restrict__ D0,
                                                         F16* __restrict__ D1) {
  const float* W = blockIdx.z ? W1 : W0;
  F16* Wt = blockIdx.z ? D1 : D0;
  __shared__ float tile[64][65];
  const int t = threadIdx.x;
  const int bx = blockIdx.x, by = blockIdx.y;
  {
    int r = t >> 4, c = (t & 15) << 2;
    const float* src = W + (size_t)(by * 64 + r) * E + bx * 64 + c;
    #pragma unroll
    for (int i = 0; i < 4; ++i) {
      float4 v = *(const float4*)(src + (size_t)i * 16 * E);
      tile[r + i * 16][c + 0] = v.x; tile[r + i * 16][c + 1] = v.y;
      tile[r + i * 16][c + 2] = v.z; tile[r + i * 16][c + 3] = v.w;
    }
  }
  __syncthreads();
  {
    int r = t >> 2, c = (t & 3) << 4;
    half8 v0, v1;
    #pragma unroll
    for (int i = 0; i < 8; ++i) v0[i] = (F16)tile[c + i][r];
    #pragma unroll
    for (int i = 0; i < 8; ++i) v1[i] = (F16)tile[c + 8 + i][r];
    F16* dst = Wt + (size_t)(bx * 64 + r) * E + by * 64 + c;
    *(half8*)dst = v0;
    *(half8*)(dst + 8) = v1;
  }
}

// ---------------- fp16 GEMM: C[M,N] = A[M,K] * Bt[N,K]^T ----------------
// Tile 64(M) x 128(N), BK=64, 4 waves (2Mx2N). Grid (N/128, M/64).
// MODE 0: single f16 out. MODE 1: fused QK (Bt 4096 rows; bn<16 -> C0 scaled
// by 1/sqrt(D), else C1). MODE 2: f32 out.
template <int MODE>
__global__ __launch_bounds__(256, 2) void gemm_bt_k(const F16* __restrict__ A,
                                                    const F16* __restrict__ Bt,
                                                    void* __restrict__ C0v,
                                                    void* __restrict__ C1v) {
  constexpr int K = 2048, N = 2048;
  __shared__ F16 sA[64 * 64];
  __shared__ F16 sB[128 * 64];
  const int t = threadIdx.x;
  const int lane = t & 63, wave = t >> 6;
  const int wr = wave >> 1, wc = wave & 1;
  const int bm = blockIdx.y, bn = blockIdx.x;

  f32x4 acc[2][4];
  #pragma unroll
  for (int mi = 0; mi < 2; ++mi)
    #pragma unroll
    for (int ni = 0; ni < 4; ++ni) acc[mi][ni] = (f32x4){0.f, 0.f, 0.f, 0.f};

  const int rb = t >> 3;                     // 0..31
  const int bofs = (t & 7) << 4;
  const int kOff = (bofs ^ ((rb & 7) << 4)) >> 1;
  const F16* aSrc = A + (size_t)(bm * 64 + rb) * K + kOff;
  const F16* bSrc = Bt + (size_t)(bn * 128 + rb) * K + kOff;
  F16* aDst = sA + t * 8;
  F16* bDst = sB + t * 8;

  for (int bk = 0; bk < K; bk += 64) {
    #pragma unroll
    for (int it = 0; it < 2; ++it)
      gload16(aSrc + (size_t)it * 32 * K + bk, aDst + it * 2048);
    #pragma unroll
    for (int it = 0; it < 4; ++it)
      gload16(bSrc + (size_t)it * 32 * K + bk, bDst + it * 2048);
    __syncthreads();
    #pragma unroll
    for (int kk = 0; kk < 2; ++kk) {
      half8 af[2], bf[4];
      const int kb = kk * 64 + ((lane >> 4) << 4);
      #pragma unroll
      for (int i = 0; i < 2; ++i) {
        const int ra = wr * 32 + i * 16 + (lane & 15);
        af[i] = *(const half8*)((const char*)sA + ra * 128 + (kb ^ ((ra & 7) << 4)));
      }
      #pragma unroll
      for (int i = 0; i < 4; ++i) {
        const int rn = wc * 64 + i * 16 + (lane & 15);
        bf[i] = *(const half8*)((const char*)sB + rn * 128 + (kb ^ ((rn & 7) << 4)));
      }
      #pragma unroll
      for (int mi = 0; mi < 2; ++mi)
        #pragma unroll
        for (int ni = 0; ni < 4; ++ni)
          acc[mi][ni] = __builtin_amdgcn_mfma_f32_16x16x32_f16(af[mi], bf[ni], acc[mi][ni], 0, 0, 0);
    }
    __syncthreads();
  }

  const float scale = (MODE == 1 && bn < 16) ? INV_SQRT_D : 1.0f;
  void* Cv = (MODE == 1 && bn >= 16) ? C1v : C0v;
  const int cb = (MODE == 1 ? (bn & 15) : bn) * 128;

  #pragma unroll
  for (int mi = 0; mi < 2; ++mi) {
    const int r0 = bm * 64 + wr * 32 + mi * 16 + ((lane >> 4) << 2);
    #pragma unroll
    for (int ni = 0; ni < 4; ++ni) {
      const int c = cb + wc * 64 + ni * 16 + (lane & 15);
      #pragma unroll
      for (int j = 0; j < 4; ++j) {
        if (MODE == 2)
          ((float*)Cv)[(size_t)(r0 + j) * N + c] = acc[mi][ni][j];
        else
          ((F16*)Cv)[(size_t)(r0 + j) * N + c] = (F16)(acc[mi][ni][j] * scale);
      }
    }
  }
}

// ---------------- flash attention (causal), 32q/wave + causal KV-split ----------------
// Q pre-scaled. Q,K: [S,E] f16; Vt: [E,S] f16 (V transposed).
// Grid 512: block = (head, 128-row qtile, kv-split half s). 4 waves x 32 q rows
// (two 16-q subtiles sharing every K/V LDS read). Split s processes tiles
// [s*(qt+1), (s+1)*(qt+1)) of 64 kv -> equal work; pair (c, c+256) = 17 tiles const.
// Output: normalized partial O (f16) -> Opart[s][h][q][128]; m,l (f32) -> mlArr.
__global__ __launch_bounds__(256, 2) void attn_fwd_k(const F16* __restrict__ Q,
                                                     const F16* __restrict__ Km,
                                                     const F16* __restrict__ Vt,
                                                     F16* __restrict__ Opart,
                                                     float* __restrict__ mlArr) {
  __shared__ F16 sK[2][64 * 128];  // [kv][d], 256B rows, swz (r&15)<<4
  __shared__ F16 sV[2][128 * 64];  // [d][kv], 128B rows, swz (r&7)<<4
  __shared__ F16 sP[4][32 * 64];   // per-wave P [q][kv], swz (r&7)<<4
  const int t = threadIdx.x, lane = t & 63, w = t >> 6;
  const int c = blockIdx.x & 255;
  const int sp = blockIdx.x >> 8;            // kv-split half
  const int h = c & 15;
  const int qi = c >> 4;                     // 0..15
  const int qt = sp ? (15 - qi) : qi;        // balanced pairing: sum 17 tiles/CU
  const int qrow0 = qt * 128 + w * 32;
  const int l15 = lane & 15, g = lane >> 4;
  const int q0 = qrow0 + l15;
  const int q1 = qrow0 + 16 + l15;

  half8 qf0[4], qf1[4];
  {
    const F16* qp0 = Q + (size_t)q0 * E + h * 128 + (g << 3);
    const F16* qp1 = Q + (size_t)q1 * E + h * 128 + (g << 3);
    #pragma unroll
    for (int kd = 0; kd < 4; ++kd) {
      qf0[kd] = *(const half8*)(qp0 + kd * 32);
      qf1[kd] = *(const half8*)(qp1 + kd * 32);
    }
  }

  f32x4 oacc0[8], oacc1[8];
  #pragma unroll
  for (int i = 0; i < 8; ++i) {
    oacc0[i] = (f32x4){0.f, 0.f, 0.f, 0.f};
    oacc1[i] = (f32x4){0.f, 0.f, 0.f, 0.f};
  }
  float m0r = -3e38f, l0r = 0.f, m1r = -3e38f, l1r = 0.f;

  const int rk = t >> 4;
  const int kcol = (((t & 15) << 4) ^ ((rk & 15) << 4)) >> 1;  // d offset (elems)
  const int rv = t >> 3;
  const int vcol = (((t & 7) << 4) ^ ((rv & 7) << 4)) >> 1;    // kv offset (elems)
  const F16* kBase = Km + (size_t)rk * E + h * 128 + kcol;
  const F16* vBase = Vt + (size_t)(h * 128 + rv) * S + vcol;
  F16* myP = (F16*)sP[w];

  auto stage = [&](int kt, int b) {
    const F16* kSrc = kBase + (size_t)kt * 64 * E;
    const F16* vSrc = vBase + kt * 64;
    #pragma unroll
    for (int it = 0; it < 4; ++it) {
      gload16(kSrc + (size_t)it * 16 * E, &sK[b][t * 8 + it * 2048]);
      gload16(vSrc + (size_t)it * 32 * S, &sV[b][t * 8 + it * 2048]);
    }
  };

  const int kb0 = sp * (qt + 1), kb1 = kb0 + qt + 1;
  stage(kb0, kb0 & 1);

  for (int kt = kb0; kt < kb1; ++kt) {
    __syncthreads();  // tile kt landed; all waves done with buf being overwritten
    if (kt + 1 < kb1) stage(kt + 1, (kt + 1) & 1);
    if (kt * 64 > qrow0 + 31) continue;  // fully-masked for this wave (uniform)
    const char* bK = (const char*)sK[kt & 1];
    const char* bV = (const char*)sV[kt & 1];

    // ---- QK^T swapped, both q-subtiles share each kf read ----
    f32x4 sa0[4], sa1[4];
    #pragma unroll
    for (int i = 0; i < 4; ++i) {
      sa0[i] = (f32x4){0.f, 0.f, 0.f, 0.f};
      sa1[i] = (f32x4){0.f, 0.f, 0.f, 0.f};
    }
    __builtin_amdgcn_s_setprio(1);
    #pragma unroll
    for (int kd = 0; kd < 4; ++kd) {
      const int kb = kd * 64 + (g << 4);
      #pragma unroll
      for (int ni = 0; ni < 4; ++ni) {
        const int rn = ni * 16 + l15;
        half8 kf = *(const half8*)(bK + rn * 256 + (kb ^ ((rn & 15) << 4)));
        sa0[ni] = __builtin_amdgcn_mfma_f32_16x16x32_f16(kf, qf0[kd], sa0[ni], 0, 0, 0);
        sa1[ni] = __builtin_amdgcn_mfma_f32_16x16x32_f16(kf, qf1[kd], sa1[ni], 0, 0, 0);
      }
    }
    __builtin_amdgcn_s_setprio(0);

    // ---- mask + in-register row max ----
    const bool diag = (kt * 64 + 63 > qrow0);
    const int kv0 = kt * 64 + g * 4;
    float mx0 = -3e38f, mx1 = -3e38f;
    #pragma unroll
    for (int ni = 0; ni < 4; ++ni) {
      #pragma unroll
      for (int j = 0; j < 4; ++j) {
        const int kv = kv0 + ni * 16 + j;
        float s0 = sa0[ni][j], s1 = sa1[ni][j];
        if (diag && kv > q0) s0 += MASK_SC;
        if (diag && kv > q1) s1 += MASK_SC;
        sa0[ni][j] = s0; sa1[ni][j] = s1;
        mx0 = fmaxf(mx0, s0); mx1 = fmaxf(mx1, s1);
      }
    }
    mx0 = fmaxf(mx0, __shfl_xor(mx0, 16));
    mx0 = fmaxf(mx0, __shfl_xor(mx0, 32));
    mx1 = fmaxf(mx1, __shfl_xor(mx1, 16));
    mx1 = fmaxf(mx1, __shfl_xor(mx1, 32));

    // ---- online softmax, defer-max THR=8 ----
    if (__any((mx0 > m0r + 8.0f) || (mx1 > m1r + 8.0f))) {
      const float mn0 = fmaxf(m0r, mx0), mn1 = fmaxf(m1r, mx1);
      const float sc0 = __expf(m0r - mn0), sc1 = __expf(m1r - mn1);
      float rs0 = 0.f, rs1 = 0.f;
      #pragma unroll
      for (int ni = 0; ni < 4; ++ni)
        #pragma unroll
        for (int j = 0; j < 4; ++j) {
          const float p0 = __expf(sa0[ni][j] - mn0);
          const float p1 = __expf(sa1[ni][j] - mn1);
          sa0[ni][j] = p0; sa1[ni][j] = p1;
          rs0 += p0; rs1 += p1;
        }
      rs0 += __shfl_xor(rs0, 16); rs0 += __shfl_xor(rs0, 32);
      rs1 += __shfl_xor(rs1, 16); rs1 += __shfl_xor(rs1, 32);
      l0r = l0r * sc0 + rs0; l1r = l1r * sc1 + rs1;
      m0r = mn0; m1r = mn1;
      #pragma unroll
      for (int df = 0; df < 8; ++df)
        #pragma unroll
        for (int j = 0; j < 4; ++j) {
          oacc0[df][j] *= sc0;
          oacc1[df][j] *= sc1;
        }
    } else {
      float rs0 = 0.f, rs1 = 0.f;
      #pragma unroll
      for (int ni = 0; ni < 4; ++ni)
        #pragma unroll
        for (int j = 0; j < 4; ++j) {
          const float p0 = __expf(sa0[ni][j] - m0r);  // bounded by e^8
          const float p1 = __expf(sa1[ni][j] - m1r);
          sa0[ni][j] = p0; sa1[ni][j] = p1;
          rs0 += p0; rs1 += p1;
        }
      rs0 += __shfl_xor(rs0, 16); rs0 += __shfl_xor(rs0, 32);
      rs1 += __shfl_xor(rs1, 16); rs1 += __shfl_xor(rs1, 32);
      l0r += rs0; l1r += rs1;
    }

    // ---- P -> sP (8B stores), wave-private ----
    {
      char* rp0 = (char*)myP + l15 * 128;
      char* rp1 = (char*)myP + (16 + l15) * 128;
      const int sz0 = (l15 & 7) << 4;
      const int sz1 = ((16 + l15) & 7) << 4;
      #pragma unroll
      for (int ni = 0; ni < 4; ++ni) {
        half4 p0, p1;
        #pragma unroll
        for (int j = 0; j < 4; ++j) { p0[j] = (F16)sa0[ni][j]; p1[j] = (F16)sa1[ni][j]; }
        *(half4*)(rp0 + ((ni * 32 + g * 8) ^ sz0)) = p0;
        *(half4*)(rp1 + ((ni * 32 + g * 8) ^ sz1)) = p1;
      }
    }

    // ---- PV: both subtiles share each vf read ----
    __builtin_amdgcn_s_setprio(1);
    #pragma unroll
    for (int kk = 0; kk < 2; ++kk) {
      const int kb = kk * 64 + (g << 4);
      half8 pa0 = *(const half8*)((const char*)myP + l15 * 128 + (kb ^ ((l15 & 7) << 4)));
      half8 pa1 = *(const half8*)((const char*)myP + (16 + l15) * 128 + (kb ^ (((16 + l15) & 7) << 4)));
      #pragma unroll
      for (int df = 0; df < 8; ++df) {
        const int rd = df * 16 + l15;
        half8 vf = *(const half8*)(bV + rd * 128 + (kb ^ ((rd & 7) << 4)));
        oacc0[df] = __builtin_amdgcn_mfma_f32_16x16x32_f16(vf, pa0, oacc0[df], 0, 0, 0);
        oacc1[df] = __builtin_amdgcn_mfma_f32_16x16x32_f16(vf, pa1, oacc1[df], 0, 0, 0);
      }
    }
    __builtin_amdgcn_s_setprio(0);
  }

  // ---- epilogue: normalized partials + (m,l) ----
  const float inv0 = (l0r > 0.f) ? 1.0f / l0r : 0.f;
  const float inv1 = (l1r > 0.f) ? 1.0f / l1r : 0.f;
  const int row0 = (sp * 16 + h) * 2048 + q0;
  const int row1 = (sp * 16 + h) * 2048 + q1;
  F16* op0 = Opart + ((size_t)row0 << 7);
  F16* op1 = Opart + ((size_t)row1 << 7);
  #pragma unroll
  for (int df = 0; df < 8; ++df) {
    half4 o0, o1;
    #pragma unroll
    for (int j = 0; j < 4; ++j) {
      o0[j] = (F16)(oacc0[df][j] * inv0);
      o1[j] = (F16)(oacc1[df][j] * inv1);
    }
    *(half4*)(op0 + df * 16 + g * 4) = o0;
    *(half4*)(op1 + df * 16 + g * 4) = o1;
  }
  if (g == 0) {
    mlArr[row0] = m0r;          mlArr[row1] = m1r;
    mlArr[65536 + row0] = l0r;  mlArr[65536 + row1] = l1r;
  }
}

// ---------------- merge the two kv-split partials ----------------
// Opart: [2][16][2048][128] f16; mlArr: m[2][16][2048], l[2][16][2048] f32.
// Om: merged [S][E] f16 (head-interleaved columns).
__global__ __launch_bounds__(256) void merge_k(const F16* __restrict__ Opart,
                                               const float* __restrict__ mlArr,
                                               F16* __restrict__ Om) {
  const int tid = blockIdx.x * 256 + threadIdx.x;
  const int row = tid >> 4;          // h*2048+q
  const int d0 = (tid & 15) << 3;
  const int h = row >> 11, q = row & 2047;
  const float m0 = mlArr[row],          l0 = mlArr[65536 + row];
  const float m1 = mlArr[32768 + row],  l1 = mlArr[98304 + row];
  const float mm = fmaxf(m0, m1);
  const float w0 = l0 * __expf(m0 - mm);
  const float w1 = l1 * __expf(m1 - mm);
  const float inv = 1.0f / (w0 + w1);
  half8 a = *(const half8*)(Opart + ((size_t)row << 7) + d0);
  half8 b = *(const half8*)(Opart + ((size_t)(32768 + row) << 7) + d0);
  half8 o;
  #pragma unroll
  for (int j = 0; j < 8; ++j)
    o[j] = (F16)((((float)a[j]) * w0 + ((float)b[j]) * w1) * inv);
  *(half8*)(Om + (size_t)q * E + h * 128 + d0) = o;
}

// ---------------- launcher ----------------
extern "C" void kernel_launch(void* const* d_in, const int* in_sizes, int n_in,
                              void* d_out, int out_size, void* d_ws, size_t ws_size,
                              hipStream_t stream) {
  const float* X  = (const float*)d_in[0];
  const float* Wq = (const float*)d_in[1];
  const float* Wk = (const float*)d_in[2];
  const float* Wv = (const float*)d_in[3];
  const float* Wo = (const float*)d_in[4];
  float* out = (float*)d_out;

  const size_t MAT = (size_t)2048 * 2048;
  F16* Xh  = (F16*)d_ws;     // X f16 [S,E]; freed after V-GEMM -> m/l scratch
  F16* Wt0 = Xh + MAT;       // Wq^T, then Wv^T
  F16* Wt1 = Wt0 + MAT;      // Wk^T, then Wo^T
  F16* Qh  = Wt1 + MAT;      // Q (pre-scaled); freed after attn -> merged O
  F16* Kh  = Qh + MAT;       // K
  F16* Vh  = Kh + MAT;       // V^T [E,S]
  float* mlArr = (float*)d_ws;        // 512 KB in freed Xh region
  F16* Opart = (F16*)d_out;           // 16 MB partials; overwritten by out-GEMM

  dim3 b256(256);
  cast_f32_f16_k<<<dim3(MAT / 2048), b256, 0, stream>>>(X, Xh);

  transpose_cast2_k<<<dim3(32, 32, 2), b256, 0, stream>>>(Wq, Wk, Wt0, Wt1);
  gemm_bt_k<1><<<dim3(32, 32), b256, 0, stream>>>(Xh, Wt0, Qh, Kh);   // Q (scaled), K

  transpose_cast2_k<<<dim3(32, 32, 2), b256, 0, stream>>>(Wv, Wo, Wt0, Wt1);
  gemm_bt_k<0><<<dim3(16, 32), b256, 0, stream>>>(Wt0, Xh, Vh, nullptr);  // V^T = Wv^T X^T

  attn_fwd_k<<<dim3(512), b256, 0, stream>>>(Qh, Kh, Vh, Opart, mlArr);

  merge_k<<<dim3(2048), b256, 0, stream>>>(Opart, mlArr, Qh);  // merged O -> Qh

  gemm_bt_k<2><<<dim3(16, 32), b256, 0, stream>>>(Qh, Wt1, out, nullptr);
}

// Round 7
// 182.000 us; speedup vs baseline: 1.0912x; 1.0912x over previous
//
#include <hip/hip_runtime.h>

#define F16 _Float16
typedef __attribute__((ext_vector_type(8))) _Float16 half8;
typedef __attribute__((ext_vector_type(4))) _Float16 half4;
typedef __attribute__((ext_vector_type(4))) float f32x4;

constexpr int S = 2048;
constexpr int E = 2048;
constexpr float MASK_NEG = -66504.0f;
constexpr float INV_SQRT_D = 0.08838834764831845f;  // 1/sqrt(128)
constexpr float MASK_SC = MASK_NEG * INV_SQRT_D;    // mask applied to pre-scaled scores

__device__ __forceinline__ void gload16(const void* g, void* l) {
  __builtin_amdgcn_global_load_lds((const __attribute__((address_space(1))) void*)g,
                                   (__attribute__((address_space(3))) void*)l, 16, 0, 0);
}

// ---------------- elementwise f32 -> f16 cast ----------------
__global__ __launch_bounds__(256) void cast_f32_f16_k(const float* __restrict__ x,
                                                      F16* __restrict__ y) {
  size_t i = ((size_t)blockIdx.x * 256 + threadIdx.x) * 8;
  float4 a = *(const float4*)(x + i);
  float4 b = *(const float4*)(x + i + 4);
  half8 h;
  h[0] = (F16)a.x; h[1] = (F16)a.y; h[2] = (F16)a.z; h[3] = (F16)a.w;
  h[4] = (F16)b.x; h[5] = (F16)b.y; h[6] = (F16)b.z; h[7] = (F16)b.w;
  *(half8*)(y + i) = h;
}

// ---------------- dual f32 [E][E] -> f16 transposed [E][E] ----------------
// z-grid selects (W0->D0) or (W1->D1); launch with gridDim.z = 1 or 2.
__global__ __launch_bounds__(256) void transpose_cast2_k(const float* __restrict__ W0,
                                                         const float* __restrict__ W1,
                                                         F16* __restrict__ D0,
                                                         F16* __restrict__ D1) {
  const float* W = blockIdx.z ? W1 : W0;
  F16* Wt = blockIdx.z ? D1 : D0;
  __shared__ float tile[64][65];
  const int t = threadIdx.x;
  const int bx = blockIdx.x, by = blockIdx.y;
  {
    int r = t >> 4, c = (t & 15) << 2;
    const float* src = W + (size_t)(by * 64 + r) * E + bx * 64 + c;
    #pragma unroll
    for (int i = 0; i < 4; ++i) {
      float4 v = *(const float4*)(src + (size_t)i * 16 * E);
      tile[r + i * 16][c + 0] = v.x; tile[r + i * 16][c + 1] = v.y;
      tile[r + i * 16][c + 2] = v.z; tile[r + i * 16][c + 3] = v.w;
    }
  }
  __syncthreads();
  {
    int r = t >> 2, c = (t & 3) << 4;
    half8 v0, v1;
    #pragma unroll
    for (int i = 0; i < 8; ++i) v0[i] = (F16)tile[c + i][r];
    #pragma unroll
    for (int i = 0; i < 8; ++i) v1[i] = (F16)tile[c + 8 + i][r];
    F16* dst = Wt + (size_t)(bx * 64 + r) * E + by * 64 + c;
    *(half8*)dst = v0;
    *(half8*)(dst + 8) = v1;
  }
}

// ---------------- fused QKV GEMM ----------------
// Grid (48, 32). Tile 64(M) x 128(N), BK=64, 4 waves (2Mx2N).
// bn>>4: 0 -> Q = X * Wqk[0:2048]^T (scaled 1/sqrt(D))
//        1 -> K = X * Wqk[2048:4096]^T
//        2 -> Vt = Wv * X^T  (A/B swapped; Wv here is Wv^T rows [E][K])
__global__ __launch_bounds__(256, 4) void qkv_gemm_k(const F16* __restrict__ X,
                                                     const F16* __restrict__ Wqk,
                                                     const F16* __restrict__ Wv,
                                                     F16* __restrict__ Qo,
                                                     F16* __restrict__ Ko,
                                                     F16* __restrict__ Vo) {
  constexpr int K = 2048, N = 2048;
  __shared__ F16 sA[64 * 64];
  __shared__ F16 sB[128 * 64];
  const int t = threadIdx.x;
  const int lane = t & 63, wave = t >> 6;
  const int wr = wave >> 1, wc = wave & 1;
  const int bm = blockIdx.y;
  const int bn = blockIdx.x;
  const int which = bn >> 4, bnl = bn & 15;

  const F16* Aop = (which == 2) ? Wv : X;
  const F16* Bop = (which == 2) ? X : (Wqk + (size_t)which * 2048 * K);
  F16* Co = (which == 0) ? Qo : (which == 1 ? Ko : Vo);
  const float scale = (which == 0) ? INV_SQRT_D : 1.0f;

  f32x4 acc[2][4];
  #pragma unroll
  for (int mi = 0; mi < 2; ++mi)
    #pragma unroll
    for (int ni = 0; ni < 4; ++ni) acc[mi][ni] = (f32x4){0.f, 0.f, 0.f, 0.f};

  const int rb = t >> 3;                     // 0..31
  const int bofs = (t & 7) << 4;
  const int kOff = (bofs ^ ((rb & 7) << 4)) >> 1;
  const F16* aSrc = Aop + (size_t)(bm * 64 + rb) * K + kOff;
  const F16* bSrc = Bop + (size_t)(bnl * 128 + rb) * K + kOff;
  F16* aDst = sA + t * 8;
  F16* bDst = sB + t * 8;

  for (int bk = 0; bk < K; bk += 64) {
    #pragma unroll
    for (int it = 0; it < 2; ++it)
      gload16(aSrc + (size_t)it * 32 * K + bk, aDst + it * 2048);
    #pragma unroll
    for (int it = 0; it < 4; ++it)
      gload16(bSrc + (size_t)it * 32 * K + bk, bDst + it * 2048);
    __syncthreads();
    #pragma unroll
    for (int kk = 0; kk < 2; ++kk) {
      half8 af[2], bf[4];
      const int kb = kk * 64 + ((lane >> 4) << 4);
      #pragma unroll
      for (int i = 0; i < 2; ++i) {
        const int ra = wr * 32 + i * 16 + (lane & 15);
        af[i] = *(const half8*)((const char*)sA + ra * 128 + (kb ^ ((ra & 7) << 4)));
      }
      #pragma unroll
      for (int i = 0; i < 4; ++i) {
        const int rn = wc * 64 + i * 16 + (lane & 15);
        bf[i] = *(const half8*)((const char*)sB + rn * 128 + (kb ^ ((rn & 7) << 4)));
      }
      #pragma unroll
      for (int mi = 0; mi < 2; ++mi)
        #pragma unroll
        for (int ni = 0; ni < 4; ++ni)
          acc[mi][ni] = __builtin_amdgcn_mfma_f32_16x16x32_f16(af[mi], bf[ni], acc[mi][ni], 0, 0, 0);
    }
    __syncthreads();
  }

  #pragma unroll
  for (int mi = 0; mi < 2; ++mi) {
    const int r0 = bm * 64 + wr * 32 + mi * 16 + ((lane >> 4) << 2);
    #pragma unroll
    for (int ni = 0; ni < 4; ++ni) {
      const int c = bnl * 128 + wc * 64 + ni * 16 + (lane & 15);
      #pragma unroll
      for (int j = 0; j < 4; ++j)
        Co[(size_t)(r0 + j) * N + c] = (F16)(acc[mi][ni][j] * scale);
    }
  }
}

// ---------------- fp16 GEMM: C[M,N] = A[M,K] * Bt[N,K]^T, f32 out ----------------
// Tile 64(M) x 128(N), BK=64, 4 waves (2Mx2N). Grid (N/128, M/64).
__global__ __launch_bounds__(256, 2) void gemm_out_k(const F16* __restrict__ A,
                                                     const F16* __restrict__ Bt,
                                                     float* __restrict__ C) {
  constexpr int K = 2048, N = 2048;
  __shared__ F16 sA[64 * 64];
  __shared__ F16 sB[128 * 64];
  const int t = threadIdx.x;
  const int lane = t & 63, wave = t >> 6;
  const int wr = wave >> 1, wc = wave & 1;
  const int bm = blockIdx.y, bn = blockIdx.x;

  f32x4 acc[2][4];
  #pragma unroll
  for (int mi = 0; mi < 2; ++mi)
    #pragma unroll
    for (int ni = 0; ni < 4; ++ni) acc[mi][ni] = (f32x4){0.f, 0.f, 0.f, 0.f};

  const int rb = t >> 3;
  const int bofs = (t & 7) << 4;
  const int kOff = (bofs ^ ((rb & 7) << 4)) >> 1;
  const F16* aSrc = A + (size_t)(bm * 64 + rb) * K + kOff;
  const F16* bSrc = Bt + (size_t)(bn * 128 + rb) * K + kOff;
  F16* aDst = sA + t * 8;
  F16* bDst = sB + t * 8;

  for (int bk = 0; bk < K; bk += 64) {
    #pragma unroll
    for (int it = 0; it < 2; ++it)
      gload16(aSrc + (size_t)it * 32 * K + bk, aDst + it * 2048);
    #pragma unroll
    for (int it = 0; it < 4; ++it)
      gload16(bSrc + (size_t)it * 32 * K + bk, bDst + it * 2048);
    __syncthreads();
    #pragma unroll
    for (int kk = 0; kk < 2; ++kk) {
      half8 af[2], bf[4];
      const int kb = kk * 64 + ((lane >> 4) << 4);
      #pragma unroll
      for (int i = 0; i < 2; ++i) {
        const int ra = wr * 32 + i * 16 + (lane & 15);
        af[i] = *(const half8*)((const char*)sA + ra * 128 + (kb ^ ((ra & 7) << 4)));
      }
      #pragma unroll
      for (int i = 0; i < 4; ++i) {
        const int rn = wc * 64 + i * 16 + (lane & 15);
        bf[i] = *(const half8*)((const char*)sB + rn * 128 + (kb ^ ((rn & 7) << 4)));
      }
      #pragma unroll
      for (int mi = 0; mi < 2; ++mi)
        #pragma unroll
        for (int ni = 0; ni < 4; ++ni)
          acc[mi][ni] = __builtin_amdgcn_mfma_f32_16x16x32_f16(af[mi], bf[ni], acc[mi][ni], 0, 0, 0);
    }
    __syncthreads();
  }

  #pragma unroll
  for (int mi = 0; mi < 2; ++mi) {
    const int r0 = bm * 64 + wr * 32 + mi * 16 + ((lane >> 4) << 2);
    #pragma unroll
    for (int ni = 0; ni < 4; ++ni) {
      const int c = bn * 128 + wc * 64 + ni * 16 + (lane & 15);
      #pragma unroll
      for (int j = 0; j < 4; ++j)
        C[(size_t)(r0 + j) * N + c] = acc[mi][ni][j];
    }
  }
}

// ---------------- flash attention (causal), swapped-operand QK^T ----------------
// Q pre-scaled by 1/sqrt(D). Q,K: [S,E] f16; Vt: [E,S] f16; O: [S,E] f16.
// 512 blocks, 4 waves x 16 q rows. LDS-staged dbuf K/V, 1 barrier/iter.
// mfma(K,Q) -> lane holds S^T column: ONE q (lane&15), 16 kv values in regs.
__global__ __launch_bounds__(256, 2) void attn_fwd_k(const F16* __restrict__ Q,
                                                     const F16* __restrict__ Km,
                                                     const F16* __restrict__ Vt,
                                                     F16* __restrict__ O) {
  __shared__ F16 sK[2][64 * 128];  // [kv][d], 256B rows, swz (r&15)<<4
  __shared__ F16 sV[2][128 * 64];  // [d][kv], 128B rows, swz (r&7)<<4
  __shared__ F16 sP[4][16 * 64];   // per-wave P [q][kv], swz (r&7)<<4
  const int t = threadIdx.x, lane = t & 63, w = t >> 6;
  const int h = blockIdx.x & 15;
  const int bq = blockIdx.x >> 4;  // 0..31
  const int qt = (bq < 16) ? (31 - bq) : (bq - 16);  // co-resident pair-sum = 31
  const int qrow0 = qt * 64 + w * 16;
  const int g = lane >> 4;         // 4-lane k-slice group
  const int myq = qrow0 + (lane & 15);

  half8 qf[4];
  {
    const F16* qp = Q + (size_t)myq * E + h * 128 + (g << 3);
    #pragma unroll
    for (int kd = 0; kd < 4; ++kd) qf[kd] = *(const half8*)(qp + kd * 32);
  }

  f32x4 oacc[8];  // O^T: oacc[df][j] = O[d=df*16+g*4+j][myq]
  #pragma unroll
  for (int i = 0; i < 8; ++i) oacc[i] = (f32x4){0.f, 0.f, 0.f, 0.f};
  float mrun = -3e38f, lrun = 0.f;

  const int rk = t >> 4;
  const int kcol = (((t & 15) << 4) ^ ((rk & 15) << 4)) >> 1;  // d offset (elems)
  const int rv = t >> 3;
  const int vcol = (((t & 7) << 4) ^ ((rv & 7) << 4)) >> 1;    // kv offset (elems)
  const F16* kBase = Km + (size_t)rk * E + h * 128 + kcol;
  const F16* vBase = Vt + (size_t)(h * 128 + rv) * S + vcol;
  F16* myP = (F16*)sP[w];

  auto stage = [&](int kt, int b) {
    const F16* kSrc = kBase + (size_t)kt * 64 * E;
    const F16* vSrc = vBase + kt * 64;
    #pragma unroll
    for (int it = 0; it < 4; ++it) {
      gload16(kSrc + (size_t)it * 16 * E, &sK[b][t * 8 + it * 2048]);
      gload16(vSrc + (size_t)it * 32 * S, &sV[b][t * 8 + it * 2048]);
    }
  };

  stage(0, 0);
  const int nt = qt + 1;

  for (int kt = 0; kt < nt; ++kt) {
    __syncthreads();  // tile kt landed; all waves done with buf being overwritten
    if (kt + 1 < nt) stage(kt + 1, (kt + 1) & 1);
    const char* bK = (const char*)sK[kt & 1];
    const char* bV = (const char*)sV[kt & 1];

    // ---- QK^T swapped: sacc[ni][j] = S[kv=kt*64+ni*16+g*4+j][myq] ----
    f32x4 sacc[4];
    #pragma unroll
    for (int i = 0; i < 4; ++i) sacc[i] = (f32x4){0.f, 0.f, 0.f, 0.f};
    __builtin_amdgcn_s_setprio(1);
    #pragma unroll
    for (int kd = 0; kd < 4; ++kd) {
      const int kb = kd * 64 + (g << 4);
      #pragma unroll
      for (int ni = 0; ni < 4; ++ni) {
        const int rn = ni * 16 + (lane & 15);
        half8 kf = *(const half8*)(bK + rn * 256 + (kb ^ ((rn & 15) << 4)));
        sacc[ni] = __builtin_amdgcn_mfma_f32_16x16x32_f16(kf, qf[kd], sacc[ni], 0, 0, 0);
      }
    }
    __builtin_amdgcn_s_setprio(0);

    // ---- mask + in-register row max (one q per lane) ----
    const bool diag = (kt == nt - 1);
    const int kv0 = kt * 64 + g * 4;
    float mx = -3e38f;
    #pragma unroll
    for (int ni = 0; ni < 4; ++ni) {
      #pragma unroll
      for (int j = 0; j < 4; ++j) {
        float s = sacc[ni][j];
        if (diag && (kv0 + ni * 16 + j) > myq) s += MASK_SC;
        sacc[ni][j] = s;
        mx = fmaxf(mx, s);
      }
    }
    mx = fmaxf(mx, __shfl_xor(mx, 16));
    mx = fmaxf(mx, __shfl_xor(mx, 32));

    // ---- online softmax with defer-max (THR=8) ----
    if (__any(mx > mrun + 8.0f)) {
      const float mnew = fmaxf(mrun, mx);
      const float sc = __expf(mrun - mnew);
      float rs = 0.f;
      #pragma unroll
      for (int ni = 0; ni < 4; ++ni)
        #pragma unroll
        for (int j = 0; j < 4; ++j) {
          const float p = __expf(sacc[ni][j] - mnew);
          sacc[ni][j] = p;
          rs += p;
        }
      rs += __shfl_xor(rs, 16);
      rs += __shfl_xor(rs, 32);
      lrun = lrun * sc + rs;
      mrun = mnew;
      #pragma unroll
      for (int df = 0; df < 8; ++df)
        #pragma unroll
        for (int j = 0; j < 4; ++j) oacc[df][j] *= sc;
    } else {
      float rs = 0.f;
      #pragma unroll
      for (int ni = 0; ni < 4; ++ni)
        #pragma unroll
        for (int j = 0; j < 4; ++j) {
          const float p = __expf(sacc[ni][j] - mrun);  // bounded by e^8
          sacc[ni][j] = p;
          rs += p;
        }
      rs += __shfl_xor(rs, 16);
      rs += __shfl_xor(rs, 32);
      lrun += rs;
    }

    // ---- P -> sP[q][kv] (8B stores, j-contiguous kv), wave-private ----
    {
      char* rowp = (char*)myP + (lane & 15) * 128;
      const int swz = ((lane & 15) & 7) << 4;
      #pragma unroll
      for (int ni = 0; ni < 4; ++ni) {
        half4 pk;
        #pragma unroll
        for (int j = 0; j < 4; ++j) pk[j] = (F16)sacc[ni][j];
        *(half4*)(rowp + ((ni * 32 + g * 8) ^ swz)) = pk;
      }
    }

    // ---- PV swapped: oacc[df] = mfma(V_frag, P_frag) -> O^T ----
    __builtin_amdgcn_s_setprio(1);
    #pragma unroll
    for (int kk = 0; kk < 2; ++kk) {
      const int kb = kk * 64 + (g << 4);
      const int ra = lane & 15;
      half8 pa = *(const half8*)((const char*)myP + ra * 128 + (kb ^ ((ra & 7) << 4)));
      #pragma unroll
      for (int df = 0; df < 8; ++df) {
        const int rd = df * 16 + (lane & 15);
        half8 vf = *(const half8*)(bV + rd * 128 + (kb ^ ((rd & 7) << 4)));
        oacc[df] = __builtin_amdgcn_mfma_f32_16x16x32_f16(vf, pa, oacc[df], 0, 0, 0);
      }
    }
    __builtin_amdgcn_s_setprio(0);
  }

  // ---- epilogue: O[myq][h*128 + df*16 + g*4 + j] ----
  const float inv = 1.0f / lrun;
  F16* orow = O + (size_t)myq * E + h * 128;
  #pragma unroll
  for (int df = 0; df < 8; ++df) {
    half4 ov;
    #pragma unroll
    for (int j = 0; j < 4; ++j) ov[j] = (F16)(oacc[df][j] * inv);
    *(half4*)(orow + df * 16 + g * 4) = ov;
  }
}

// ---------------- launcher ----------------
extern "C" void kernel_launch(void* const* d_in, const int* in_sizes, int n_in,
                              void* d_out, int out_size, void* d_ws, size_t ws_size,
                              hipStream_t stream) {
  const float* X  = (const float*)d_in[0];
  const float* Wq = (const float*)d_in[1];
  const float* Wk = (const float*)d_in[2];
  const float* Wv = (const float*)d_in[3];
  const float* Wo = (const float*)d_in[4];
  float* out = (float*)d_out;

  const size_t MAT = (size_t)2048 * 2048;
  F16* Xh  = (F16*)d_ws;     // slot0: X f16; after mega-GEMM reused as attn out
  F16* WqT = Xh + MAT;       // slot1: Wq^T; after mega-GEMM reused as Wo^T
  F16* WkT = WqT + MAT;      // slot2: Wk^T (contiguous after WqT -> 4096-row view)
  F16* WvT = WkT + MAT;      // slot3: Wv^T
  F16* Qh  = WvT + MAT;      // slot4: Q (pre-scaled by 1/sqrt(D))
  F16* Kh  = Qh + MAT;       // slot5: K
  F16* Vh  = (F16*)d_out;    // Vt [E,S] f16 in d_out scratch (8 MB of 16 MB)
  // workspace: 6 * 8 MiB = 48 MiB

  dim3 b256(256);
  cast_f32_f16_k<<<dim3(MAT / 2048), b256, 0, stream>>>(X, Xh);

  transpose_cast2_k<<<dim3(32, 32, 2), b256, 0, stream>>>(Wq, Wk, WqT, WkT);
  transpose_cast2_k<<<dim3(32, 32, 1), b256, 0, stream>>>(Wv, Wv, WvT, WvT);

  qkv_gemm_k<<<dim3(48, 32), b256, 0, stream>>>(Xh, WqT, WvT, Qh, Kh, Vh);

  transpose_cast2_k<<<dim3(32, 32, 1), b256, 0, stream>>>(Wo, Wo, WqT, WqT);

  attn_fwd_k<<<dim3(512), b256, 0, stream>>>(Qh, Kh, Vh, Xh);  // attn out -> Xh

  gemm_out_k<<<dim3(16, 32), b256, 0, stream>>>(Xh, WqT, out);
}